// Round 5
// baseline (553.888 us; speedup 1.0000x reference)
//
#include <hip/hip_runtime.h>
#include <math.h>

#define COMMITMENT_COST 0.25f
#define DECAY 0.99f
#define EPSILON 1e-05f
#define KCODES 1024
#define DIM 256
#define NTOK 32768

// out-buffer float offsets (concatenated return tuple)
#define O_QUANT 0
#define O_LOSS  8388608
#define O_IDX   8388609
#define O_CS    8421377
#define O_EMAW  8422401
#define O_EMB   8684545

// scratch lives in the new_embedding slot (262144 floats, written LAST by emaw):
// [0,1024) esq | [1024,33792) zsq | [33792,66560) bucket |
// [66560,67584) cnt | [67584,68609) off | [68609,69633) cursor
#define SE_ESQ    0
#define SE_ZSQ    1024
#define SE_BUCKET 33792
#define SE_CNT    66560
#define SE_OFF    67584
#define SE_CURSOR 68609

// ------- sq_kernel: zsq[n], esq[k], zero cnt & loss (one dispatch) -------
__global__ void sq_kernel(const float* __restrict__ z, const float* __restrict__ E,
                          float* __restrict__ zsq, float* __restrict__ esq,
                          int* __restrict__ cnt, float* __restrict__ loss) {
    const int b = blockIdx.x;
    const int wave = threadIdx.x >> 6;
    const int lane = threadIdx.x & 63;
    if (b < NTOK / 4) {
        int token = b * 4 + wave;
        float4 v = ((const float4*)(z + (size_t)token * DIM))[lane];
        float s = v.x * v.x + v.y * v.y + v.z * v.z + v.w * v.w;
        #pragma unroll
        for (int off = 32; off > 0; off >>= 1) s += __shfl_down(s, off);
        if (lane == 0) zsq[token] = s;
        if (b == 0 && threadIdx.x == 0) loss[0] = 0.0f;
    } else {
        int eb = b - NTOK / 4;
        int k = eb * 4 + wave;
        float4 v = ((const float4*)(E + (size_t)k * DIM))[lane];
        float s = v.x * v.x + v.y * v.y + v.z * v.z + v.w * v.w;
        #pragma unroll
        for (int off = 32; off > 0; off >>= 1) s += __shfl_down(s, off);
        if (lane == 0) esq[k] = s;
        if (threadIdx.x < 4) cnt[eb * 4 + threadIdx.x] = 0;
    }
}

// ---------------- fused distances + argmin + histogram ----------------
// d = fl(fl(||z||^2 + ||e||^2) - 2*z.e) at magnitude ~256, first-index ties.
// block 256 thr; tile 64 tok x 256 codes; K-tiles 256; 32-d chunks.
// thread: r=tid>>4 (4 tokens), c=tid&15 (16 codes c+16j) -> all LDS reads
// are <=2-way bank aliased (free): zv 144r%32={0,16}, ev 36c%32=4c (16 addr
// on 8 quads, 4-lane broadcast each).
__global__ __launch_bounds__(256) void dist_argmin_kernel(
        const float* __restrict__ z, const float* __restrict__ E,
        const float* __restrict__ esq, const float* __restrict__ zsq,
        float* __restrict__ idx_out, int* __restrict__ cnt) {
    __shared__ float zs[64 * 36];
    __shared__ float es[256 * 36];

    const int tid = threadIdx.x;
    const int r = tid >> 4;          // 0..15 -> tokens r*4 .. r*4+3
    const int c = tid & 15;          // codes c + 16*j, j=0..15
    const int tok0 = blockIdx.x * 64;

    float An[4];
    #pragma unroll
    for (int i = 0; i < 4; ++i) An[i] = zsq[tok0 + r * 4 + i];

    float best[4];
    int bidx[4];
    #pragma unroll
    for (int i = 0; i < 4; ++i) { best[i] = 3.4e38f; bidx[i] = 0x7fffffff; }

    for (int kt = 0; kt < 4; ++kt) {
        const int k0 = kt * 256;
        float sq[16];
        #pragma unroll
        for (int j = 0; j < 16; ++j) sq[j] = esq[k0 + c + 16 * j];

        float acc[4][16];
        #pragma unroll
        for (int i = 0; i < 4; ++i)
            #pragma unroll
            for (int j = 0; j < 16; ++j) acc[i][j] = 0.0f;

        for (int dc = 0; dc < 8; ++dc) {
            const int d0 = dc * 32;
            __syncthreads();
            // stage z tile: 64 tok x 32 d (512 f4, 2/thread, coalesced)
            #pragma unroll
            for (int q = 0; q < 2; ++q) {
                int g = tid + 256 * q;
                int row = g >> 3, col = (g & 7) * 4;
                *(float4*)(zs + row * 36 + col) =
                    *(const float4*)(z + (size_t)(tok0 + row) * DIM + d0 + col);
            }
            // stage E tile: 256 codes x 32 d (2048 f4, 8/thread, coalesced)
            #pragma unroll
            for (int q = 0; q < 8; ++q) {
                int g = tid + 256 * q;
                int row = g >> 3, col = (g & 7) * 4;
                *(float4*)(es + row * 36 + col) =
                    *(const float4*)(E + (size_t)(k0 + row) * DIM + d0 + col);
            }
            __syncthreads();
            #pragma unroll
            for (int dg = 0; dg < 8; ++dg) {
                float4 zv[4];
                #pragma unroll
                for (int i = 0; i < 4; ++i)
                    zv[i] = *(const float4*)(zs + (r * 4 + i) * 36 + dg * 4);
                #pragma unroll
                for (int j = 0; j < 16; ++j) {
                    float4 ev = *(const float4*)(es + (c + 16 * j) * 36 + dg * 4);
                    #pragma unroll
                    for (int i = 0; i < 4; ++i) {
                        acc[i][j] = fmaf(zv[i].x, ev.x, acc[i][j]);
                        acc[i][j] = fmaf(zv[i].y, ev.y, acc[i][j]);
                        acc[i][j] = fmaf(zv[i].z, ev.z, acc[i][j]);
                        acc[i][j] = fmaf(zv[i].w, ev.w, acc[i][j]);
                    }
                }
            }
        }
        // epilogue: mirror reference rounding sequence
        #pragma unroll
        for (int i = 0; i < 4; ++i)
            #pragma unroll
            for (int j = 0; j < 16; ++j) {
                float S = An[i] + sq[j];
                float dv = S - 2.0f * acc[i][j];
                int gi = k0 + c + 16 * j;
                if (dv < best[i] || (dv == best[i] && gi < bidx[i])) {
                    best[i] = dv; bidx[i] = gi;
                }
            }
    }
    // cross-lane merge over the 16 c-lanes of each r-group
    #pragma unroll
    for (int i = 0; i < 4; ++i) {
        float v = best[i]; int id = bidx[i];
        #pragma unroll
        for (int m = 1; m < 16; m <<= 1) {
            float ov = __shfl_xor(v, m);
            int   oi = __shfl_xor(id, m);
            if (ov < v || (ov == v && oi < id)) { v = ov; id = oi; }
        }
        if (c == 0) {
            idx_out[tok0 + r * 4 + i] = (float)id;
            atomicAdd(&cnt[id], 1);
        }
    }
}

// ------- scan + cluster-size finalize (1 block, 1024 thr) -------
__global__ __launch_bounds__(1024) void scan_cs_kernel(
        const int* __restrict__ cnt, int* __restrict__ off,
        int* __restrict__ cursor, const float* __restrict__ ema_cs,
        float* __restrict__ cs_out) {
    __shared__ int s[KCODES];
    __shared__ float f[KCODES];
    const int k = threadIdx.x;
    int v = cnt[k];
    s[k] = v;
    float pre = ema_cs[k] * DECAY + (1.0f - DECAY) * (float)v;
    f[k] = pre;
    __syncthreads();
    for (int d = 1; d < KCODES; d <<= 1) {
        int add = (k >= d) ? s[k - d] : 0;
        __syncthreads();
        s[k] += add;
        __syncthreads();
    }
    int excl = s[k] - v;
    off[k] = excl;
    cursor[k] = excl;
    if (k == KCODES - 1) off[KCODES] = s[k];
    // n = sum(pre)
    for (int st = 512; st > 0; st >>= 1) {
        if (k < st) f[k] += f[k + st];
        __syncthreads();
    }
    float n = f[0];
    cs_out[k] = (pre + EPSILON) / (n + KCODES * EPSILON) * n;
}

// ------- scatter + quantized gather + loss (fused) -------
__global__ __launch_bounds__(256) void scatterquant_kernel(
        const float* __restrict__ z, const float* __restrict__ E,
        const float* __restrict__ idx_f, int* __restrict__ cursor,
        int* __restrict__ bucket, float* __restrict__ quant,
        float* __restrict__ loss_acc) {
    __shared__ float ls[4];
    const int wave = threadIdx.x >> 6;
    const int lane = threadIdx.x & 63;
    const int token = blockIdx.x * 4 + wave;
    const int idx = (int)idx_f[token];

    if (lane == 0) {
        int p = atomicAdd(&cursor[idx], 1);
        bucket[p] = token;
    }

    const float4 ev = *(const float4*)(E + (size_t)idx * DIM + lane * 4);
    const float4 zv = *(const float4*)(z + (size_t)token * DIM + lane * 4);
    *(float4*)(quant + (size_t)token * DIM + lane * 4) = ev;

    float dx = zv.x - ev.x, dy = zv.y - ev.y, dz = zv.z - ev.z, dww = zv.w - ev.w;
    float l = dx * dx + dy * dy + dz * dz + dww * dww;
    #pragma unroll
    for (int off = 32; off > 0; off >>= 1) l += __shfl_down(l, off);
    if (lane == 0) ls[wave] = l;
    __syncthreads();
    if (threadIdx.x == 0)
        atomicAdd(loss_acc, ls[0] + ls[1] + ls[2] + ls[3]);
}

// ------- dw[k] = sum of assigned z rows (CSR, no atomics) -------
__global__ __launch_bounds__(256) void dwsum_kernel(
        const float* __restrict__ z, const int* __restrict__ off,
        const int* __restrict__ bucket, float* __restrict__ dw) {
    const int k = blockIdx.x;
    const int s = off[k], e = off[k + 1];
    float acc = 0.0f;
    for (int t = s; t < e; ++t) {
        int token = bucket[t];
        acc += z[(size_t)token * DIM + threadIdx.x];
    }
    dw[(size_t)k * DIM + threadIdx.x] = acc;
}

// ------- new_ema_w & new_embedding (+ loss finalize) -------
__global__ __launch_bounds__(256) void emaw_kernel(
        const float* __restrict__ ema_w, const float* __restrict__ cs,
        float* __restrict__ emaw_inout /* holds dw */, float* __restrict__ emb_out,
        float* __restrict__ loss_inout) {
    const int i = blockIdx.x * 256 + threadIdx.x;
    const int k = i >> 6;
    float4 d = ((const float4*)emaw_inout)[i];
    float4 w = ((const float4*)ema_w)[i];
    float4 nw;
    nw.x = w.x * DECAY + (1.0f - DECAY) * d.x;
    nw.y = w.y * DECAY + (1.0f - DECAY) * d.y;
    nw.z = w.z * DECAY + (1.0f - DECAY) * d.z;
    nw.w = w.w * DECAY + (1.0f - DECAY) * d.w;
    ((float4*)emaw_inout)[i] = nw;
    float inv = 1.0f / cs[k];
    float4 e; e.x = nw.x * inv; e.y = nw.y * inv; e.z = nw.z * inv; e.w = nw.w * inv;
    ((float4*)emb_out)[i] = e;
    if (i == 0)
        loss_inout[0] = COMMITMENT_COST * loss_inout[0] / (float)((size_t)NTOK * DIM);
}

extern "C" void kernel_launch(void* const* d_in, const int* in_sizes, int n_in,
                              void* d_out, int out_size, void* d_ws, size_t ws_size,
                              hipStream_t stream) {
    const float* z      = (const float*)d_in[0];
    const float* E      = (const float*)d_in[1];
    const float* ema_cs = (const float*)d_in[2];
    const float* ema_w  = (const float*)d_in[3];
    float* out = (float*)d_out;

    float* emb    = out + O_EMB;
    float* esq    = emb + SE_ESQ;
    float* zsq    = emb + SE_ZSQ;
    int*   bucket = (int*)(emb + SE_BUCKET);
    int*   cnt    = (int*)(emb + SE_CNT);
    int*   off    = (int*)(emb + SE_OFF);
    int*   cursor = (int*)(emb + SE_CURSOR);

    sq_kernel<<<NTOK / 4 + KCODES / 4, 256, 0, stream>>>(z, E, zsq, esq, cnt,
                                                         out + O_LOSS);
    dist_argmin_kernel<<<NTOK / 64, 256, 0, stream>>>(z, E, esq, zsq,
                                                      out + O_IDX, cnt);
    scan_cs_kernel<<<1, 1024, 0, stream>>>(cnt, off, cursor, ema_cs, out + O_CS);
    scatterquant_kernel<<<NTOK / 4, 256, 0, stream>>>(z, E, out + O_IDX, cursor,
                                                      bucket, out + O_QUANT,
                                                      out + O_LOSS);
    dwsum_kernel<<<KCODES, 256, 0, stream>>>(z, off, bucket, out + O_EMAW);
    emaw_kernel<<<(KCODES * DIM / 4) / 256, 256, 0, stream>>>(ema_w, out + O_CS,
                                                              out + O_EMAW, emb,
                                                              out + O_LOSS);
}

// Round 6
// 506.194 us; speedup vs baseline: 1.0942x; 1.0942x over previous
//
#include <hip/hip_runtime.h>
#include <math.h>

#define COMMITMENT_COST 0.25f
#define DECAY 0.99f
#define EPSILON 1e-05f
#define KCODES 1024
#define DIM 256
#define NTOK 32768

// out-buffer float offsets (concatenated return tuple)
#define O_QUANT 0
#define O_LOSS  8388608
#define O_IDX   8388609
#define O_CS    8421377
#define O_EMAW  8422401
#define O_EMB   8684545

// scratch in the new_embedding slot (262144 floats, written LAST by emaw).
// O_EMB is an ODD float offset -> +1 makes packed u64 8-byte aligned.
#define SE_PACKED 1        // u64 x 32768  -> floats [1, 65537)
#define SE_ESQ    65544
#define SE_ZSQ    66568    // 32768 floats
#define SE_BUCKET 99336    // 32768 ints
#define SE_OFF    132104   // 1025 ints
#define SE_CURSOR 133192   // 1024 ints

// ------- sq_kernel: zsq[n], esq[k], zero dw & loss (one dispatch) -------
__global__ void sq_kernel(const float* __restrict__ z, const float* __restrict__ E,
                          float* __restrict__ zsq, float* __restrict__ esq,
                          float* __restrict__ dw, float* __restrict__ loss) {
    const int b = blockIdx.x;
    const int wave = threadIdx.x >> 6;
    const int lane = threadIdx.x & 63;
    if (b < NTOK / 4) {
        int token = b * 4 + wave;
        float4 v = ((const float4*)(z + (size_t)token * DIM))[lane];
        float s = v.x * v.x + v.y * v.y + v.z * v.z + v.w * v.w;
        #pragma unroll
        for (int off = 32; off > 0; off >>= 1) s += __shfl_down(s, off);
        if (lane == 0) zsq[token] = s;
        if (b == 0 && threadIdx.x == 0) loss[0] = 0.0f;
    } else {
        int eb = b - NTOK / 4;                 // 0..255
        int k = eb * 4 + wave;
        float4 v = ((const float4*)(E + (size_t)k * DIM))[lane];
        float s = v.x * v.x + v.y * v.y + v.z * v.z + v.w * v.w;
        #pragma unroll
        for (int off = 32; off > 0; off >>= 1) s += __shfl_down(s, off);
        if (lane == 0) esq[k] = s;
        float4 zero4 = {0.f, 0.f, 0.f, 0.f};
        ((float4*)dw)[eb * 256 + threadIdx.x] = zero4;   // 256*256*4 = 262144
    }
}

// ---------------- fused distances + argmin (K-split + atomicMin) ----------
// d = fl(fl(||z||^2 + ||e||^2) - 2*z.e) at magnitude ~256 (>0 always since
// ||z||^2 ~ 256 dominates). Pack (dist_bits<<32)|idx -> u64 atomicMin gives
// global min with first-index tie-break. Per-acc accumulation order is
// unchanged from the passing round (dc -> dg -> x,y,z,w).
// block 256 thr; tile 64 tok x 128 codes (1 of 8 K-chunks); 32-d chunks;
// thread: r=tid>>4 (4 tokens), c=tid&15 (8 codes c+16j). LDS 27.6 KB.
__global__ __launch_bounds__(256) void dist_argmin_kernel(
        const float* __restrict__ z, const float* __restrict__ E,
        const float* __restrict__ esq, const float* __restrict__ zsq,
        unsigned long long* __restrict__ packed) {
    __shared__ float zs[64 * 36];
    __shared__ float es[128 * 36];

    const int tid = threadIdx.x;
    const int r = tid >> 4;          // 0..15 -> tokens r*4 .. r*4+3
    const int c = tid & 15;          // codes c + 16*j, j=0..7
    const int ks   = blockIdx.x & 7;
    const int tok0 = (blockIdx.x >> 3) * 64;
    const int k0   = ks * 128;

    float An[4];
    #pragma unroll
    for (int i = 0; i < 4; ++i) An[i] = zsq[tok0 + r * 4 + i];

    float sq[8];
    #pragma unroll
    for (int j = 0; j < 8; ++j) sq[j] = esq[k0 + c + 16 * j];

    float acc[4][8];
    #pragma unroll
    for (int i = 0; i < 4; ++i)
        #pragma unroll
        for (int j = 0; j < 8; ++j) acc[i][j] = 0.0f;

    for (int dc = 0; dc < 8; ++dc) {
        const int d0 = dc * 32;
        __syncthreads();
        // stage z tile: 64 tok x 32 d (512 f4, 2/thread, coalesced)
        #pragma unroll
        for (int q = 0; q < 2; ++q) {
            int g = tid + 256 * q;
            int row = g >> 3, col = (g & 7) * 4;
            *(float4*)(zs + row * 36 + col) =
                *(const float4*)(z + (size_t)(tok0 + row) * DIM + d0 + col);
        }
        // stage E tile: 128 codes x 32 d (1024 f4, 4/thread, coalesced)
        #pragma unroll
        for (int q = 0; q < 4; ++q) {
            int g = tid + 256 * q;
            int row = g >> 3, col = (g & 7) * 4;
            *(float4*)(es + row * 36 + col) =
                *(const float4*)(E + (size_t)(k0 + row) * DIM + d0 + col);
        }
        __syncthreads();
        #pragma unroll
        for (int dg = 0; dg < 8; ++dg) {
            float4 zv[4];
            #pragma unroll
            for (int i = 0; i < 4; ++i)
                zv[i] = *(const float4*)(zs + (r * 4 + i) * 36 + dg * 4);
            #pragma unroll
            for (int j = 0; j < 8; ++j) {
                float4 ev = *(const float4*)(es + (c + 16 * j) * 36 + dg * 4);
                #pragma unroll
                for (int i = 0; i < 4; ++i) {
                    acc[i][j] = fmaf(zv[i].x, ev.x, acc[i][j]);
                    acc[i][j] = fmaf(zv[i].y, ev.y, acc[i][j]);
                    acc[i][j] = fmaf(zv[i].z, ev.z, acc[i][j]);
                    acc[i][j] = fmaf(zv[i].w, ev.w, acc[i][j]);
                }
            }
        }
    }
    // epilogue: mirror reference rounding sequence, local then cross-lane min
    #pragma unroll
    for (int i = 0; i < 4; ++i) {
        float v = 3.4e38f; int id = 0x7fffffff;
        #pragma unroll
        for (int j = 0; j < 8; ++j) {
            float S = An[i] + sq[j];
            float dv = S - 2.0f * acc[i][j];
            int gi = k0 + c + 16 * j;
            if (dv < v || (dv == v && gi < id)) { v = dv; id = gi; }
        }
        #pragma unroll
        for (int m = 1; m < 16; m <<= 1) {
            float ov = __shfl_xor(v, m);
            int   oi = __shfl_xor(id, m);
            if (ov < v || (ov == v && oi < id)) { v = ov; id = oi; }
        }
        if (c == 0) {
            unsigned long long p =
                ((unsigned long long)__float_as_uint(v) << 32) | (unsigned)id;
            atomicMin(&packed[tok0 + r * 4 + i], p);
        }
    }
}

// ------- scan_cs: unpack idx + histogram + scan + cluster-size -------
__global__ __launch_bounds__(1024) void scan_cs_kernel(
        const unsigned long long* __restrict__ packed, float* __restrict__ idx_out,
        int* __restrict__ off, int* __restrict__ cursor,
        const float* __restrict__ ema_cs, float* __restrict__ cs_out) {
    __shared__ int h[KCODES];
    __shared__ float f[KCODES];
    const int k = threadIdx.x;
    h[k] = 0;
    __syncthreads();
    #pragma unroll
    for (int q = 0; q < 32; ++q) {
        int t = k + 1024 * q;
        int idx = (int)(unsigned)(packed[t] & 0xFFFFFFFFull);
        idx_out[t] = (float)idx;
        atomicAdd(&h[idx], 1);
    }
    __syncthreads();
    int v = h[k];
    float pre = ema_cs[k] * DECAY + (1.0f - DECAY) * (float)v;
    f[k] = pre;
    int s = v;
    // inclusive scan via LDS (reuse h)
    for (int d = 1; d < KCODES; d <<= 1) {
        int add = (k >= d) ? h[k - d] : 0;
        __syncthreads();
        h[k] += add;
        __syncthreads();
    }
    int excl = h[k] - v;
    off[k] = excl;
    cursor[k] = excl;
    if (k == KCODES - 1) off[KCODES] = h[k];
    for (int st = 512; st > 0; st >>= 1) {
        if (k < st) f[k] += f[k + st];
        __syncthreads();
    }
    float n = f[0];
    cs_out[k] = (pre + EPSILON) / (n + KCODES * EPSILON) * n;
    (void)s;
}

// ------- scatter + quantized gather + loss (fused) -------
__global__ __launch_bounds__(256) void scatterquant_kernel(
        const float* __restrict__ z, const float* __restrict__ E,
        const float* __restrict__ idx_f, int* __restrict__ cursor,
        int* __restrict__ bucket, float* __restrict__ quant,
        float* __restrict__ loss_acc) {
    __shared__ float ls[4];
    const int wave = threadIdx.x >> 6;
    const int lane = threadIdx.x & 63;
    const int token = blockIdx.x * 4 + wave;
    const int idx = (int)idx_f[token];

    if (lane == 0) {
        int p = atomicAdd(&cursor[idx], 1);
        bucket[p] = token;
    }

    const float4 ev = *(const float4*)(E + (size_t)idx * DIM + lane * 4);
    const float4 zv = *(const float4*)(z + (size_t)token * DIM + lane * 4);
    *(float4*)(quant + (size_t)token * DIM + lane * 4) = ev;

    float dx = zv.x - ev.x, dy = zv.y - ev.y, dz = zv.z - ev.z, dww = zv.w - ev.w;
    float l = dx * dx + dy * dy + dz * dz + dww * dww;
    #pragma unroll
    for (int off = 32; off > 0; off >>= 1) l += __shfl_down(l, off);
    if (lane == 0) ls[wave] = l;
    __syncthreads();
    if (threadIdx.x == 0)
        atomicAdd(loss_acc, ls[0] + ls[1] + ls[2] + ls[3]);
}

// ------- dwsum: chunk-parallel CSR segment-sum (skew-immune) -------
// 512 blocks x 64 bucket entries; run-boundary atomics only.
__global__ __launch_bounds__(256) void dwsum_kernel(
        const float* __restrict__ z, const int* __restrict__ off,
        const int* __restrict__ bucket, float* __restrict__ dw) {
    __shared__ int sb[64];
    const int chunk0 = blockIdx.x * 64;
    const int chunk1 = chunk0 + 64;
    const int d = threadIdx.x;
    if (d < 64) sb[d] = bucket[chunk0 + d];
    __syncthreads();
    // binary search: largest k with off[k] <= chunk0
    int lo = 0, hi = KCODES;
    while (lo + 1 < hi) {
        int mid = (lo + hi) >> 1;
        if (off[mid] <= chunk0) lo = mid; else hi = mid;
    }
    int k = lo;
    int t = chunk0;
    while (t < chunk1) {
        int e = off[k + 1]; if (e > chunk1) e = chunk1;
        if (e > t) {
            float acc = 0.0f;
            for (int u = t; u < e; ++u)
                acc += z[(size_t)sb[u - chunk0] * DIM + d];
            atomicAdd(&dw[(size_t)k * DIM + d], acc);
            t = e;
        }
        ++k;
    }
}

// ------- new_ema_w & new_embedding (+ loss finalize) -------
__global__ __launch_bounds__(256) void emaw_kernel(
        const float* __restrict__ ema_w, const float* __restrict__ cs,
        float* __restrict__ emaw_inout /* holds dw */, float* __restrict__ emb_out,
        float* __restrict__ loss_inout) {
    const int i = blockIdx.x * 256 + threadIdx.x;
    const int k = i >> 6;
    float4 d = ((const float4*)emaw_inout)[i];
    float4 w = ((const float4*)ema_w)[i];
    float4 nw;
    nw.x = w.x * DECAY + (1.0f - DECAY) * d.x;
    nw.y = w.y * DECAY + (1.0f - DECAY) * d.y;
    nw.z = w.z * DECAY + (1.0f - DECAY) * d.z;
    nw.w = w.w * DECAY + (1.0f - DECAY) * d.w;
    ((float4*)emaw_inout)[i] = nw;
    float inv = 1.0f / cs[k];
    float4 e; e.x = nw.x * inv; e.y = nw.y * inv; e.z = nw.z * inv; e.w = nw.w * inv;
    ((float4*)emb_out)[i] = e;
    if (i == 0)
        loss_inout[0] = COMMITMENT_COST * loss_inout[0] / (float)((size_t)NTOK * DIM);
}

extern "C" void kernel_launch(void* const* d_in, const int* in_sizes, int n_in,
                              void* d_out, int out_size, void* d_ws, size_t ws_size,
                              hipStream_t stream) {
    const float* z      = (const float*)d_in[0];
    const float* E      = (const float*)d_in[1];
    const float* ema_cs = (const float*)d_in[2];
    const float* ema_w  = (const float*)d_in[3];
    float* out = (float*)d_out;

    float* emb = out + O_EMB;
    unsigned long long* packed = (unsigned long long*)(emb + SE_PACKED);
    float* esq    = emb + SE_ESQ;
    float* zsq    = emb + SE_ZSQ;
    int*   bucket = (int*)(emb + SE_BUCKET);
    int*   off    = (int*)(emb + SE_OFF);
    int*   cursor = (int*)(emb + SE_CURSOR);

    hipMemsetAsync(packed, 0xFF, (size_t)NTOK * 8, stream);

    sq_kernel<<<NTOK / 4 + KCODES / 4, 256, 0, stream>>>(z, E, zsq, esq,
                                                         out + O_EMAW, out + O_LOSS);
    dist_argmin_kernel<<<(NTOK / 64) * 8, 256, 0, stream>>>(z, E, esq, zsq, packed);
    scan_cs_kernel<<<1, 1024, 0, stream>>>(packed, out + O_IDX, off, cursor,
                                           ema_cs, out + O_CS);
    scatterquant_kernel<<<NTOK / 4, 256, 0, stream>>>(z, E, out + O_IDX, cursor,
                                                      bucket, out + O_QUANT,
                                                      out + O_LOSS);
    dwsum_kernel<<<NTOK / 64, 256, 0, stream>>>(z, off, bucket, out + O_EMAW);
    emaw_kernel<<<(KCODES * DIM / 4) / 256, 256, 0, stream>>>(ema_w, out + O_CS,
                                                              out + O_EMAW, emb,
                                                              out + O_LOSS);
}